// Round 7
// baseline (238.293 us; speedup 1.0000x reference)
//
#include <hip/hip_runtime.h>

typedef short s16x8 __attribute__((ext_vector_type(8)));
typedef float f32x4 __attribute__((ext_vector_type(4)));

#define DIM     512
#define BATCH   256
#define NTRI    131328          // (512*512+512)/2
#define FDIM    131840          // 512 + NTRI
#define KBLOCKS 2060            // FDIM / 64
#define BN      64
#define NTILES  8               // 512 / BN
#define CCH     64              // K-chunks: grid 512 = exactly 2 wg/CU, %8==0

__device__ __forceinline__ unsigned short f2bf(float f) {
  __bf16 h = (__bf16)f;                       // RNE hardware cvt
  return __builtin_bit_cast(unsigned short, h);
}
__device__ __forceinline__ float bf2f(unsigned short s) {
  union { unsigned u; float f; } v; v.u = (unsigned)s << 16; return v.f;
}
__device__ __forceinline__ unsigned pk2(float a, float b) {
  return (unsigned)f2bf(a) | ((unsigned)f2bf(b) << 16);
}
// bijective on aligned 8-runs and uniform over any 64-consecutive-m wave
__device__ __forceinline__ int swz(int m) { return (m ^ (m >> 2)) & 7; }

__device__ __forceinline__ void dma16(const void* g, void* l) {
  __builtin_amdgcn_global_load_lds(
      (const __attribute__((address_space(1))) void*)g,
      (__attribute__((address_space(3))) void*)l, 16, 0, 0);
}

// ---------- setup: pair table (blocks 0..511) + x transpose (blocks 512..1023) ----------
__global__ void setup(unsigned* __restrict__ table, const float* __restrict__ x,
                      unsigned short* __restrict__ Xt) {
  int bid = blockIdx.x;
  if (bid < 512) {
    int i = bid;
    int base = i * DIM - (i * (i - 1)) / 2;
    int len = DIM - i;
    for (int t = threadIdx.x; t < len; t += blockDim.x)
      table[base + t] = ((unsigned)i << 16) | (unsigned)(i + t);
  } else {
    int t = (bid - 512) * blockDim.x + threadIdx.x;   // 131072
    int r = t & (BATCH - 1);
    int c = t >> 8;
    Xt[c * BATCH + r] = f2bf(x[r * DIM + c]);
  }
}

// ---------- feature materialization: per-kb 32KB pre-swizzled LDS images ----------
__global__ __launch_bounds__(512)
void featgen(const unsigned* __restrict__ table,
             const unsigned short* __restrict__ Xt,   // [512][256] bf16
             uint4* __restrict__ Feat)                // [KBLOCKS][2048] uint4
{
  __shared__ uint4 img[2048];                  // 32 KB [m][slot]
  const int kb = blockIdx.x;
  const int tid = threadIdx.x;
  const int s8 = tid >> 6;                     // wave-uniform k-group
  const int lane = tid & 63;
  const int f0 = kb * 64 + s8 * 8;

  if (f0 < DIM) {                              // linear features (kb < 8)
    #pragma unroll
    for (int mb = 0; mb < 4; ++mb) {
      int m = mb * 64 + lane;
      unsigned short v[8];
      #pragma unroll
      for (int e = 0; e < 8; ++e) v[e] = Xt[(f0 + e) * BATCH + m];
      uint4 pk;
      pk.x = (unsigned)v[0] | ((unsigned)v[1] << 16);
      pk.y = (unsigned)v[2] | ((unsigned)v[3] << 16);
      pk.z = (unsigned)v[4] | ((unsigned)v[5] << 16);
      pk.w = (unsigned)v[6] | ((unsigned)v[7] << 16);
      img[m * 8 + (s8 ^ swz(m))] = pk;
    }
  } else {
    int p0 = f0 - DIM;
    unsigned t0 = table[p0], t7 = table[p0 + 7];
    if ((t0 >> 16) == (t7 >> 16)) {            // fast path: same i, contiguous j
      int i = (int)(t0 >> 16), j0 = (int)(t0 & 0xffffu);
      #pragma unroll
      for (int mb = 0; mb < 4; ++mb) {
        int m = mb * 64 + lane;
        float xi = bf2f(Xt[i * BATCH + m]);
        float pr[8];
        #pragma unroll
        for (int e = 0; e < 8; ++e) pr[e] = xi * bf2f(Xt[(j0 + e) * BATCH + m]);
        uint4 pk = make_uint4(pk2(pr[0], pr[1]), pk2(pr[2], pr[3]),
                              pk2(pr[4], pr[5]), pk2(pr[6], pr[7]));
        img[m * 8 + (s8 ^ swz(m))] = pk;
      }
    } else {                                   // run boundary (rare)
      unsigned tt[8];
      #pragma unroll
      for (int e = 0; e < 8; ++e) tt[e] = table[p0 + e];
      #pragma unroll
      for (int mb = 0; mb < 4; ++mb) {
        int m = mb * 64 + lane;
        float pr[8];
        #pragma unroll
        for (int e = 0; e < 8; ++e)
          pr[e] = bf2f(Xt[(tt[e] >> 16) * BATCH + m]) * bf2f(Xt[(tt[e] & 0xffffu) * BATCH + m]);
        uint4 pk = make_uint4(pk2(pr[0], pr[1]), pk2(pr[2], pr[3]),
                              pk2(pr[4], pr[5]), pk2(pr[6], pr[7]));
        img[m * 8 + (s8 ^ swz(m))] = pk;
      }
    }
  }
  __syncthreads();
  uint4* out = Feat + (size_t)kb * 2048;       // linear 32KB stream-out
  #pragma unroll
  for (int p = 0; p < 4; ++p) out[p * 512 + tid] = img[p * 512 + tid];
}

// ---------- GEMM: partial[chunk] = feat[256,Kc] @ W[n0:n0+64,:]^T (bf16 partials) ----------
__global__ __launch_bounds__(512, 4)
void qgemm(const uint4* __restrict__ Feat,      // pre-swizzled per-kb images
           const float* __restrict__ W,         // [512][131840] f32
           unsigned short* __restrict__ partial, // [C][256][512] bf16
           int C)
{
  __shared__ unsigned short As[2 * BATCH * 64]; // 64 KB double-buffered feature tiles
  __shared__ unsigned short Ws[2 * 64 * 64];    // 16 KB double-buffered weight tiles
  const int chunk = blockIdx.x % C;             // C%8==0 -> chunk's 8 ntiles share an XCD
  const int ntile = blockIdx.x / C;
  const int kb0 = (KBLOCKS * chunk) / C;
  const int kb1 = (KBLOCKS * (chunk + 1)) / C;
  const int n0 = ntile * BN;
  const int tid = threadIdx.x;
  const int lane = tid & 63;
  const int wave = tid >> 6;
  const int wm = wave & 3;                      // 4 waves along M
  const int wn = wave >> 2;                     // 2 waves along N
  const int lm = lane & 15;
  const int lk = lane >> 4;

  const int wr0 = tid >> 4;                     // Ws staging: 16 lanes = 256B of one W row
  const int wc16 = tid & 15;

  f32x4 acc[4][2] = {};
  f32x4 wregC[2], wregN[2];

  const char* fsrc0 = (const char*)Feat + tid * 16;
  char* adst0 = (char*)As + tid * 16;
  const float* wp0 = W + (size_t)(n0 + wr0) * FDIM + wc16 * 4;
  const size_t wrow32 = (size_t)32 * FDIM;

  // ---- prologue: tile kb0 in flight ----
  {
    const char* src = fsrc0 + (size_t)kb0 * 32768;
    #pragma unroll
    for (int p = 0; p < 4; ++p) dma16(src + p * 8192, adst0 + p * 8192);
    #pragma unroll
    for (int it = 0; it < 2; ++it)
      wregC[it] = *(const f32x4*)(wp0 + it * wrow32 + (size_t)kb0 * 64);
  }

  // ---- steady loop (last iteration peeled) ----
  for (int kb = kb0; kb < kb1 - 1; ++kb) {
    const int pc = (kb - kb0) & 1;
    // issue next tile: 4 DMA + 2 W loads (6 VMEM stay in flight through compute)
    {
      const char* src = fsrc0 + (size_t)(kb + 1) * 32768;
      char* dst = adst0 + (pc ^ 1) * 32768;
      #pragma unroll
      for (int p = 0; p < 4; ++p) dma16(src + p * 8192, dst + p * 8192);
      #pragma unroll
      for (int it = 0; it < 2; ++it)
        wregN[it] = *(const f32x4*)(wp0 + it * wrow32 + (size_t)(kb + 1) * 64);
    }
    __builtin_amdgcn_sched_barrier(0);          // pin issues above the Ws store
    // store Ws(t): compiler waits vmcnt(6) -> retires DMA(t)+W(t), keeps t+1 in flight
    #pragma unroll
    for (int it = 0; it < 2; ++it) {
      int r = wr0 + it * 32;
      int slot = (wc16 >> 1) ^ swz(r);
      *(uint2*)((char*)Ws + pc * 8192 + r * 128 + slot * 16 + (wc16 & 1) * 8) =
          make_uint2(pk2(wregC[it][0], wregC[it][1]), pk2(wregC[it][2], wregC[it][3]));
    }
    asm volatile("s_waitcnt lgkmcnt(0)" ::: "memory");
    __builtin_amdgcn_sched_barrier(0);
    __builtin_amdgcn_s_barrier();               // As(t)/Ws(t) visible to all waves
    // compute(t): all 12 ds_reads first, then setprio-wrapped 16-MFMA cluster
    {
      const char* asb = (const char*)As + pc * 32768;
      const char* wsb = (const char*)Ws + pc * 8192;
      s16x8 bfr[2][2], afr[2][4];
      #pragma unroll
      for (int ks = 0; ks < 2; ++ks) {
        #pragma unroll
        for (int nf = 0; nf < 2; ++nf) {
          int n = wn * 32 + nf * 16 + lm;
          int slot = (ks * 4 + lk) ^ swz(n);
          bfr[ks][nf] = *(const s16x8*)(wsb + n * 128 + slot * 16);
        }
        #pragma unroll
        for (int mf = 0; mf < 4; ++mf) {
          int mm = wm * 64 + mf * 16 + lm;
          int slot = (ks * 4 + lk) ^ swz(mm);
          afr[ks][mf] = *(const s16x8*)(asb + mm * 128 + slot * 16);
        }
      }
      __builtin_amdgcn_s_setprio(1);
      #pragma unroll
      for (int ks = 0; ks < 2; ++ks)
        #pragma unroll
        for (int mf = 0; mf < 4; ++mf)
          #pragma unroll
          for (int nf = 0; nf < 2; ++nf)
            acc[mf][nf] = __builtin_amdgcn_mfma_f32_16x16x32_bf16(afr[ks][mf], bfr[ks][nf], acc[mf][nf], 0, 0, 0);
      __builtin_amdgcn_s_setprio(0);
    }
    __builtin_amdgcn_s_barrier();               // protect buffers before next iter's writes
    wregC[0] = wregN[0]; wregC[1] = wregN[1];
  }

  // ---- peeled last iteration ----
  {
    const int pc = (kb1 - 1 - kb0) & 1;
    #pragma unroll
    for (int it = 0; it < 2; ++it) {
      int r = wr0 + it * 32;
      int slot = (wc16 >> 1) ^ swz(r);
      *(uint2*)((char*)Ws + pc * 8192 + r * 128 + slot * 16 + (wc16 & 1) * 8) =
          make_uint2(pk2(wregC[it][0], wregC[it][1]), pk2(wregC[it][2], wregC[it][3]));
    }
    asm volatile("s_waitcnt lgkmcnt(0)" ::: "memory");
    __builtin_amdgcn_s_barrier();
    const char* asb = (const char*)As + pc * 32768;
    const char* wsb = (const char*)Ws + pc * 8192;
    s16x8 bfr[2][2], afr[2][4];
    #pragma unroll
    for (int ks = 0; ks < 2; ++ks) {
      #pragma unroll
      for (int nf = 0; nf < 2; ++nf) {
        int n = wn * 32 + nf * 16 + lm;
        int slot = (ks * 4 + lk) ^ swz(n);
        bfr[ks][nf] = *(const s16x8*)(wsb + n * 128 + slot * 16);
      }
      #pragma unroll
      for (int mf = 0; mf < 4; ++mf) {
        int mm = wm * 64 + mf * 16 + lm;
        int slot = (ks * 4 + lk) ^ swz(mm);
        afr[ks][mf] = *(const s16x8*)(asb + mm * 128 + slot * 16);
      }
    }
    #pragma unroll
    for (int ks = 0; ks < 2; ++ks)
      #pragma unroll
      for (int mf = 0; mf < 4; ++mf)
        #pragma unroll
        for (int nf = 0; nf < 2; ++nf)
          acc[mf][nf] = __builtin_amdgcn_mfma_f32_16x16x32_bf16(afr[ks][mf], bfr[ks][nf], acc[mf][nf], 0, 0, 0);
  }

  // ---- write partial tile (bf16) ----
  unsigned short* pout = partial + (size_t)chunk * (BATCH * DIM);
  #pragma unroll
  for (int mf = 0; mf < 4; ++mf) {
    #pragma unroll
    for (int nf = 0; nf < 2; ++nf) {
      int mrow = wm * 64 + mf * 16 + lk * 4;    // C/D: col=lane&15, row=(lane>>4)*4+reg
      int ncol = n0 + wn * 32 + nf * 16 + lm;
      #pragma unroll
      for (int r = 0; r < 4; ++r)
        pout[(size_t)(mrow + r) * DIM + ncol] = f2bf(acc[mf][nf][r]);
    }
  }
}

// ---------- reductions (bf16 partials, uint4 = 8 elems per load) ----------
__global__ void reduce_h(const unsigned short* __restrict__ partial, const float* __restrict__ bias,
                         unsigned short* __restrict__ Ht, int C) {
  int u = blockIdx.x * blockDim.x + threadIdx.x;   // 16384
  int t8 = u * 8;                                  // t = b*512 + o
  int b = t8 >> 9;
  int o0 = t8 & (DIM - 1);
  float s[8];
  #pragma unroll
  for (int e = 0; e < 8; ++e) s[e] = bias[o0 + e];
  for (int c = 0; c < C; ++c) {
    uint4 v = *(const uint4*)(partial + (size_t)c * (BATCH * DIM) + t8);
    unsigned w[4] = {v.x, v.y, v.z, v.w};
    #pragma unroll
    for (int p = 0; p < 4; ++p) {
      s[2*p]   += bf2f((unsigned short)(w[p] & 0xffffu));
      s[2*p+1] += bf2f((unsigned short)(w[p] >> 16));
    }
  }
  #pragma unroll
  for (int e = 0; e < 8; ++e)
    Ht[(o0 + e) * BATCH + b] = f2bf(s[e]);         // transposed bf16 for layer-2 featgen
}

__global__ void reduce_out(const unsigned short* __restrict__ partial, const float* __restrict__ bias,
                           float* __restrict__ out, int C) {
  int u = blockIdx.x * blockDim.x + threadIdx.x;   // 16384
  int t8 = u * 8;
  int o0 = t8 & (DIM - 1);
  float s[8];
  #pragma unroll
  for (int e = 0; e < 8; ++e) s[e] = bias[o0 + e];
  for (int c = 0; c < C; ++c) {
    uint4 v = *(const uint4*)(partial + (size_t)c * (BATCH * DIM) + t8);
    unsigned w[4] = {v.x, v.y, v.z, v.w};
    #pragma unroll
    for (int p = 0; p < 4; ++p) {
      s[2*p]   += bf2f((unsigned short)(w[p] & 0xffffu));
      s[2*p+1] += bf2f((unsigned short)(w[p] >> 16));
    }
  }
  f32x4 lo = {s[0], s[1], s[2], s[3]};
  f32x4 hi = {s[4], s[5], s[6], s[7]};
  *(f32x4*)(out + t8) = lo;
  *(f32x4*)(out + t8 + 4) = hi;
}

extern "C" void kernel_launch(void* const* d_in, const int* in_sizes, int n_in,
                              void* d_out, int out_size, void* d_ws, size_t ws_size,
                              hipStream_t stream) {
  const float* x  = (const float*)d_in[0];
  const float* W0 = (const float*)d_in[1];
  const float* b0 = (const float*)d_in[2];
  const float* W1 = (const float*)d_in[3];
  const float* b1 = (const float*)d_in[4];
  float* out = (float*)d_out;

  char* ws = (char*)d_ws;
  unsigned* table    = (unsigned*)ws;                        // 525,312 B
  unsigned short* Xt = (unsigned short*)(ws + 525312);       // 262,144 B
  unsigned short* Ht = (unsigned short*)(ws + 787456);       // 262,144 B
  uint4* Feat        = (uint4*)(ws + 1049600);               // 67,502,080 B (2060*32KB)
  size_t feat_end    = 1049600 + (size_t)KBLOCKS * 32768;
  unsigned short* partial = (unsigned short*)(ws + feat_end); // C * 256 KiB (bf16)

  size_t avail = (ws_size > feat_end) ? (ws_size - feat_end) : 0;
  int C = (int)(avail / ((size_t)BATCH * DIM * sizeof(unsigned short)));
  if (C > CCH) C = CCH;
  if (C < 1)  C = 1;

  setup<<<dim3(1024), dim3(256), 0, stream>>>(table, x, Xt);

  featgen<<<dim3(KBLOCKS), dim3(512), 0, stream>>>(table, Xt, Feat);
  qgemm<<<dim3(NTILES * C), dim3(512), 0, stream>>>(Feat, W0, partial, C);
  reduce_h<<<dim3(64), dim3(256), 0, stream>>>(partial, b0, Ht, C);

  featgen<<<dim3(KBLOCKS), dim3(512), 0, stream>>>(table, Ht, Feat);
  qgemm<<<dim3(NTILES * C), dim3(512), 0, stream>>>(Feat, W1, partial, C);
  reduce_out<<<dim3(64), dim3(256), 0, stream>>>(partial, b1, out, C);
}